// Round 1
// baseline (225.620 us; speedup 1.0000x reference)
//
#include <hip/hip_runtime.h>

#define D 64
#define ITEM_PAD 100000
#define LSEQ 200
#define BATCH 4096
#define NEG_W 0.1f

// ---------------------------------------------------------------------------
// Gram kernel: G += W_rows^T @ W_rows over nrows rows of width D=64.
// idx == nullptr -> rows are W[r]; else rows are W[idx[r]] (gather).
// Block: 256 threads = 16x16 thread grid, each thread owns a 4x4 tile of the
// 64x64 output. 16 rows staged per LDS chunk. atomicAdd merge at the end.
// ---------------------------------------------------------------------------
__global__ void gram_kernel(const float* __restrict__ W, const int* __restrict__ idx,
                            int nrows, float* __restrict__ G) {
    __shared__ float tile[16 * D];   // 16 rows x 64 floats = 4 KB
    const int t    = threadIdx.x;
    const int ti   = t >> 4;         // 0..15 -> output rows ti*4..ti*4+3
    const int tj   = t & 15;         // 0..15 -> output cols tj*4..tj*4+3
    const int row  = ti;             // staging: row within chunk
    const int col4 = tj;             // staging: float4 slot within row

    float acc[4][4] = {{0.f,0.f,0.f,0.f},{0.f,0.f,0.f,0.f},
                       {0.f,0.f,0.f,0.f},{0.f,0.f,0.f,0.f}};

    const int nchunks = (nrows + 15) >> 4;
    for (int c = blockIdx.x; c < nchunks; c += gridDim.x) {
        const int r = (c << 4) + row;
        float4 v = make_float4(0.f, 0.f, 0.f, 0.f);
        if (r < nrows) {
            const int src = idx ? idx[r] : r;
            v = *(const float4*)(W + (size_t)src * D + col4 * 4);
        }
        __syncthreads();   // protect previous chunk's LDS reads
        *(float4*)(tile + row * D + col4 * 4) = v;
        __syncthreads();

        #pragma unroll
        for (int r2 = 0; r2 < 16; ++r2) {
            float xi[4], xj[4];
            *(float4*)xi = *(const float4*)(tile + r2 * D + ti * 4);
            *(float4*)xj = *(const float4*)(tile + r2 * D + tj * 4);
            #pragma unroll
            for (int a = 0; a < 4; ++a)
                #pragma unroll
                for (int b2 = 0; b2 < 4; ++b2)
                    acc[a][b2] += xi[a] * xj[b2];
        }
    }

    #pragma unroll
    for (int a = 0; a < 4; ++a)
        #pragma unroll
        for (int b2 = 0; b2 < 4; ++b2)
            atomicAdd(G + (ti * 4 + a) * D + (tj * 4 + b2), acc[a][b2]);
}

// ---------------------------------------------------------------------------
// pos_data_loss: one block per batch row b. uh[d] = user_W[uids[b],d]*h[d]
// staged in LDS. Each wave handles 4 (b,l) pairs per iteration: 16 lanes x
// float4 cover one 256B item row (coalesced). 4-step xor-shuffle reduction
// within the 16-lane group yields hpq; accumulate 0.9*hpq^2 - 2*hpq.
// Padding id (100000) is masked (contributes exactly 0).
// ---------------------------------------------------------------------------
__global__ void pos_loss_kernel(const int* __restrict__ uids,
                                const int* __restrict__ pos_iids,
                                const float* __restrict__ user_W,
                                const float* __restrict__ item_W,
                                const float* __restrict__ h,
                                float* __restrict__ acc_out) {
    __shared__ float uh[D];
    __shared__ float red[4];
    const int b = blockIdx.x;
    const int t = threadIdx.x;

    if (t < D) {
        const int uid = uids[b];
        uh[t] = user_W[(size_t)uid * D + t] * h[t];
    }
    __syncthreads();

    const int lane = t & 63;
    const int wave = t >> 6;     // 0..3
    const int p    = lane >> 4;  // pair slot within wave, 0..3
    const int q    = lane & 15;  // float4 slot within row, 0..15

    float myuh[4];
    *(float4*)myuh = *(const float4*)(uh + q * 4);

    float local = 0.f;
    for (int l0 = 0; l0 < LSEQ; l0 += 16) {
        const int l = l0 + wave * 4 + p;
        const bool valid = (l < LSEQ);
        const int iid = valid ? pos_iids[(size_t)b * LSEQ + l] : ITEM_PAD;
        float partial = 0.f;
        if (iid != ITEM_PAD) {
            float rowv[4];
            *(float4*)rowv = *(const float4*)(item_W + (size_t)iid * D + q * 4);
            partial = myuh[0]*rowv[0] + myuh[1]*rowv[1] + myuh[2]*rowv[2] + myuh[3]*rowv[3];
        }
        // reduce across the 16-lane group (q dimension)
        partial += __shfl_xor(partial, 1);
        partial += __shfl_xor(partial, 2);
        partial += __shfl_xor(partial, 4);
        partial += __shfl_xor(partial, 8);
        if (q == 0 && valid) {
            local += (1.0f - NEG_W) * partial * partial - 2.0f * partial;
        }
    }

    // block reduction: full wave butterfly, then LDS across 4 waves
    local += __shfl_xor(local, 1);
    local += __shfl_xor(local, 2);
    local += __shfl_xor(local, 4);
    local += __shfl_xor(local, 8);
    local += __shfl_xor(local, 16);
    local += __shfl_xor(local, 32);
    if (lane == 0) red[wave] = local;
    __syncthreads();
    if (t == 0) {
        atomicAdd(acc_out, red[0] + red[1] + red[2] + red[3]);
    }
}

// ---------------------------------------------------------------------------
// finalize: out = NEG_W * sum_ij G_item[i,j]*G_user[i,j]*h[i]*h[j] + pos_loss
// ---------------------------------------------------------------------------
__global__ void finalize_kernel(const float* __restrict__ ws,
                                const float* __restrict__ h,
                                float* __restrict__ out) {
    __shared__ float red[4];
    const int t = threadIdx.x;
    const float* Gi = ws;
    const float* Gu = ws + D * D;
    float s = 0.f;
    for (int k = t; k < D * D; k += 256) {
        const int i = k >> 6, j = k & 63;
        s += Gi[k] * Gu[k] * h[i] * h[j];
    }
    s += __shfl_xor(s, 1);
    s += __shfl_xor(s, 2);
    s += __shfl_xor(s, 4);
    s += __shfl_xor(s, 8);
    s += __shfl_xor(s, 16);
    s += __shfl_xor(s, 32);
    const int lane = t & 63, wave = t >> 6;
    if (lane == 0) red[wave] = s;
    __syncthreads();
    if (t == 0) {
        const float tot = red[0] + red[1] + red[2] + red[3];
        out[0] = NEG_W * tot + ws[2 * D * D];
    }
}

extern "C" void kernel_launch(void* const* d_in, const int* in_sizes, int n_in,
                              void* d_out, int out_size, void* d_ws, size_t ws_size,
                              hipStream_t stream) {
    const int*   uids     = (const int*)d_in[0];
    const int*   pos_iids = (const int*)d_in[1];
    const float* user_W   = (const float*)d_in[2];
    const float* item_W   = (const float*)d_in[3];
    const float* h        = (const float*)d_in[4];
    float* out = (float*)d_out;
    float* ws  = (float*)d_ws;

    // ws layout (floats): [0,4096) G_item, [4096,8192) G_user, [8192] pos_loss
    hipMemsetAsync(ws, 0, (2 * D * D + 1) * sizeof(float), stream);

    gram_kernel<<<256, 256, 0, stream>>>(item_W, nullptr, ITEM_PAD + 1, ws);
    gram_kernel<<<64, 256, 0, stream>>>(user_W, uids, BATCH, ws + D * D);
    pos_loss_kernel<<<BATCH, 256, 0, stream>>>(uids, pos_iids, user_W, item_W, h,
                                               ws + 2 * D * D);
    finalize_kernel<<<1, 256, 0, stream>>>(ws, h, out);
}

// Round 2
// 150.880 us; speedup vs baseline: 1.4954x; 1.4954x over previous
//
#include <hip/hip_runtime.h>

#define D 64
#define ITEM_PAD 100000
#define LSEQ 200
#define BATCH 4096
#define NEG_W 0.1f
#define NBI 512   // gram_item partial blocks
#define NBU 64    // gram_user partial blocks

// ws layout (floats):
//   [0,      4096)  G_item (final)
//   [4096,   8192)  G_user (final)
//   [8192,  12288)  pos partials (fast) / [8192] atomic slot (fallback)
//   [12288, 12288+NBI*4096)            Pitem per-block partials   (fast only)
//   [12288+NBI*4096, +NBU*4096)        Puser per-block partials   (fast only)

// ---------------------------------------------------------------------------
// Gram: G += W_rows^T @ W_rows, 16x16 threads each owning a 4x4 output tile,
// 16-row LDS chunks. partial=1 -> store per-block G to out+blockIdx*4096;
// partial=0 -> atomicAdd into shared final G (fallback path, v1-proven).
// ---------------------------------------------------------------------------
__global__ void gram_kernel(const float* __restrict__ W, const int* __restrict__ idx,
                            int nrows, float* __restrict__ out, int partial) {
    __shared__ float tile[16 * D];
    const int t  = threadIdx.x;
    const int ti = t >> 4;
    const int tj = t & 15;

    float acc[4][4] = {{0.f,0.f,0.f,0.f},{0.f,0.f,0.f,0.f},
                       {0.f,0.f,0.f,0.f},{0.f,0.f,0.f,0.f}};

    const int nchunks = (nrows + 15) >> 4;
    for (int c = blockIdx.x; c < nchunks; c += gridDim.x) {
        const int r = (c << 4) + ti;
        float4 v = make_float4(0.f, 0.f, 0.f, 0.f);
        if (r < nrows) {
            const int src = idx ? idx[r] : r;
            v = *(const float4*)(W + (size_t)src * D + tj * 4);
        }
        __syncthreads();
        *(float4*)(tile + ti * D + tj * 4) = v;
        __syncthreads();

        #pragma unroll
        for (int r2 = 0; r2 < 16; ++r2) {
            float xi[4], xj[4];
            *(float4*)xi = *(const float4*)(tile + r2 * D + ti * 4);
            *(float4*)xj = *(const float4*)(tile + r2 * D + tj * 4);
            #pragma unroll
            for (int a = 0; a < 4; ++a)
                #pragma unroll
                for (int b2 = 0; b2 < 4; ++b2)
                    acc[a][b2] += xi[a] * xj[b2];
        }
    }

    if (partial) {
        float* dst = out + (size_t)blockIdx.x * 4096;
        #pragma unroll
        for (int a = 0; a < 4; ++a)
            *(float4*)(dst + (ti * 4 + a) * D + tj * 4) = *(const float4*)acc[a];
    } else {
        #pragma unroll
        for (int a = 0; a < 4; ++a)
            #pragma unroll
            for (int b2 = 0; b2 < 4; ++b2)
                atomicAdd(out + (ti * 4 + a) * D + (tj * 4 + b2), acc[a][b2]);
    }
}

// ---------------------------------------------------------------------------
// Reduce per-block gram partials into final G (fast path only).
// Grid = 320: blocks 0..255 item (16 k-slices x 16 p-slices of 32),
//             blocks 256..319 user (16 k-slices x 4 p-slices of 16).
// atomicAdd colliders per address: 16 (item) / 4 (user) - negligible.
// ---------------------------------------------------------------------------
__global__ void reduce_gram_kernel(float* __restrict__ ws) {
    const float* Pi = ws + 12288;
    const float* Pu = ws + 12288 + (size_t)NBI * 4096;
    const int b = blockIdx.x, t = threadIdx.x;
    if (b < 256) {
        const int k  = (b & 15) * 256 + t;
        const int p0 = (b >> 4) * (NBI / 16);
        float s = 0.f;
        #pragma unroll 4
        for (int p = 0; p < NBI / 16; ++p) s += Pi[(size_t)(p0 + p) * 4096 + k];
        atomicAdd(ws + k, s);
    } else {
        const int bb = b - 256;
        const int k  = (bb & 15) * 256 + t;
        const int p0 = (bb >> 4) * (NBU / 4);
        float s = 0.f;
        #pragma unroll 4
        for (int p = 0; p < NBU / 4; ++p) s += Pu[(size_t)(p0 + p) * 4096 + k];
        atomicAdd(ws + 4096 + k, s);
    }
}

// ---------------------------------------------------------------------------
// pos_data_loss, one block per batch row. Indices staged in LDS, all 13 row
// gathers issued into registers before the reduce chains (single latency
// exposure). partial=1 -> out[b] = block sum; else atomicAdd(out, sum).
// ---------------------------------------------------------------------------
__global__ void pos_loss_kernel(const int* __restrict__ uids,
                                const int* __restrict__ pos_iids,
                                const float* __restrict__ user_W,
                                const float* __restrict__ item_W,
                                const float* __restrict__ h,
                                float* __restrict__ out, int partial) {
    __shared__ float uh[D];
    __shared__ int sidx[LSEQ];
    __shared__ float red[4];
    const int b = blockIdx.x;
    const int t = threadIdx.x;

    if (t < LSEQ) sidx[t] = pos_iids[(size_t)b * LSEQ + t];
    if (t >= 192) {
        const int j = t - 192;
        uh[j] = user_W[(size_t)uids[b] * D + j] * h[j];
    }
    __syncthreads();

    const int lane = t & 63;
    const int wave = t >> 6;
    const int p    = lane >> 4;   // 0..3
    const int q    = lane & 15;   // 0..15
    const int base = wave * 4 + p; // 0..15

    const float4 u4 = *(const float4*)(uh + q * 4);

    int ids[13];
    #pragma unroll
    for (int k = 0; k < 13; ++k) {
        const int l = base + 16 * k;
        ids[k] = (l < LSEQ) ? sidx[l] : ITEM_PAD;
    }

    float4 rows[13];
    #pragma unroll
    for (int k = 0; k < 13; ++k) {
        float4 v = make_float4(0.f, 0.f, 0.f, 0.f);
        if (ids[k] != ITEM_PAD)
            v = *(const float4*)(item_W + (size_t)ids[k] * D + q * 4);
        rows[k] = v;
    }

    float local = 0.f;
    #pragma unroll
    for (int k = 0; k < 13; ++k) {
        float s = u4.x * rows[k].x + u4.y * rows[k].y + u4.z * rows[k].z + u4.w * rows[k].w;
        s += __shfl_xor(s, 1);
        s += __shfl_xor(s, 2);
        s += __shfl_xor(s, 4);
        s += __shfl_xor(s, 8);
        if (q == 0)
            local += (1.0f - NEG_W) * s * s - 2.0f * s;
    }

    local += __shfl_xor(local, 1);
    local += __shfl_xor(local, 2);
    local += __shfl_xor(local, 4);
    local += __shfl_xor(local, 8);
    local += __shfl_xor(local, 16);
    local += __shfl_xor(local, 32);
    if (lane == 0) red[wave] = local;
    __syncthreads();
    if (t == 0) {
        const float tot = red[0] + red[1] + red[2] + red[3];
        if (partial) out[b] = tot;
        else atomicAdd(out, tot);
    }
}

// ---------------------------------------------------------------------------
// finalize: out = NEG_W * sum_ij Gi*Gu*h_i*h_j + sum(pos partials)
// ---------------------------------------------------------------------------
__global__ void finalize_kernel(const float* __restrict__ ws,
                                const float* __restrict__ h,
                                float* __restrict__ out, int npos) {
    __shared__ float red[4];
    const int t = threadIdx.x;
    float s = 0.f;
    for (int k = t; k < 4096; k += 256) {
        const int i = k >> 6, j = k & 63;
        s += ws[k] * ws[4096 + k] * h[i] * h[j];
    }
    float ps = 0.f;
    for (int k = t; k < npos; k += 256) ps += ws[8192 + k];
    float v = NEG_W * s + ps;
    v += __shfl_xor(v, 1);
    v += __shfl_xor(v, 2);
    v += __shfl_xor(v, 4);
    v += __shfl_xor(v, 8);
    v += __shfl_xor(v, 16);
    v += __shfl_xor(v, 32);
    const int lane = t & 63, wave = t >> 6;
    if (lane == 0) red[wave] = v;
    __syncthreads();
    if (t == 0) out[0] = red[0] + red[1] + red[2] + red[3];
}

extern "C" void kernel_launch(void* const* d_in, const int* in_sizes, int n_in,
                              void* d_out, int out_size, void* d_ws, size_t ws_size,
                              hipStream_t stream) {
    const int*   uids     = (const int*)d_in[0];
    const int*   pos_iids = (const int*)d_in[1];
    const float* user_W   = (const float*)d_in[2];
    const float* item_W   = (const float*)d_in[3];
    const float* h        = (const float*)d_in[4];
    float* out = (float*)d_out;
    float* ws  = (float*)d_ws;

    const size_t need = (size_t)(12288 + (NBI + NBU) * 4096) * sizeof(float);
    if (ws_size >= need) {
        // fast path: per-block partials, no high-collision atomics
        hipMemsetAsync(ws, 0, 8192 * sizeof(float), stream);  // G areas only
        gram_kernel<<<NBI, 256, 0, stream>>>(item_W, nullptr, ITEM_PAD + 1,
                                             ws + 12288, 1);
        gram_kernel<<<NBU, 256, 0, stream>>>(user_W, uids, BATCH,
                                             ws + 12288 + (size_t)NBI * 4096, 1);
        pos_loss_kernel<<<BATCH, 256, 0, stream>>>(uids, pos_iids, user_W, item_W, h,
                                                   ws + 8192, 1);
        reduce_gram_kernel<<<320, 256, 0, stream>>>(ws);
        finalize_kernel<<<1, 256, 0, stream>>>(ws, h, out, 4096);
    } else {
        // fallback: v1-proven layout (33 KB), atomics
        hipMemsetAsync(ws, 0, (8192 + 1) * sizeof(float), stream);
        gram_kernel<<<256, 256, 0, stream>>>(item_W, nullptr, ITEM_PAD + 1, ws, 0);
        gram_kernel<<<64, 256, 0, stream>>>(user_W, uids, BATCH, ws + 4096, 0);
        pos_loss_kernel<<<BATCH, 256, 0, stream>>>(uids, pos_iids, user_W, item_W, h,
                                                   ws + 8192, 0);
        finalize_kernel<<<1, 256, 0, stream>>>(ws, h, out, 1);
    }
}

// Round 3
// 126.324 us; speedup vs baseline: 1.7860x; 1.1944x over previous
//
#include <hip/hip_runtime.h>

#define D 64
#define ITEM_PAD 100000
#define LSEQ 200
#define BATCH 4096
#define NEG_W 0.1f
#define NBI 512                         // gram_item partial blocks
#define NBU 64                          // gram_user partial blocks
#define GSZ (D * D)                     // 4096
#define PITEM_OFF 0
#define PUSER_OFF ((size_t)NBI * GSZ)              // 2,097,152 floats
#define POS_OFF   (PUSER_OFF + (size_t)NBU * GSZ)  // 2,359,296
#define WS2_OFF   (POS_OFF + BATCH)                // 2,363,392
#define WS_FLOATS (WS2_OFF + 256)                  // 2,363,648 (~9.45 MB)

// ---------------------------------------------------------------------------
// Kernel A: all partials in ONE launch. No atomics, no pre-zeroed memory.
//   blocks [0, NBI)            : item-Gram partial -> Pitem[blk]
//   blocks [NBI, NBI+NBU)      : user-Gram partial -> Puser[blk-NBI]
//   blocks [NBI+NBU, +BATCH)   : pos-loss row partial -> pos[blk-NBI-NBU]
// Gram blocks go first (longest-job-first) so they start immediately and the
// many short pos blocks stream in around them.
// ---------------------------------------------------------------------------
__global__ void fused_partials(const int* __restrict__ uids,
                               const int* __restrict__ pos_iids,
                               const float* __restrict__ user_W,
                               const float* __restrict__ item_W,
                               const float* __restrict__ h,
                               float* __restrict__ ws) {
    __shared__ float smem[16 * D];   // 4 KB; gram tile, pos path aliases into it
    const int bid = blockIdx.x;
    const int t   = threadIdx.x;

    if (bid < NBI + NBU) {
        // ---- Gram partial: acc 4x4 per thread over 16-row LDS chunks ----
        const bool item = (bid < NBI);
        const float* __restrict__ W = item ? item_W : user_W;
        const int* __restrict__ idx = item ? nullptr : uids;
        const int nrows   = item ? (ITEM_PAD + 1) : BATCH;
        const int stride  = item ? NBI : NBU;
        const int b0      = item ? bid : bid - NBI;
        float* __restrict__ out =
            ws + (item ? PITEM_OFF + (size_t)b0 * GSZ : PUSER_OFF + (size_t)b0 * GSZ);

        const int ti = t >> 4;
        const int tj = t & 15;
        float acc[4][4] = {{0.f,0.f,0.f,0.f},{0.f,0.f,0.f,0.f},
                           {0.f,0.f,0.f,0.f},{0.f,0.f,0.f,0.f}};

        const int nchunks = (nrows + 15) >> 4;
        for (int c = b0; c < nchunks; c += stride) {
            const int r = (c << 4) + ti;
            float4 v = make_float4(0.f, 0.f, 0.f, 0.f);
            if (r < nrows) {
                const int src = idx ? idx[r] : r;
                v = *(const float4*)(W + (size_t)src * D + tj * 4);
            }
            __syncthreads();
            *(float4*)(smem + ti * D + tj * 4) = v;
            __syncthreads();

            #pragma unroll
            for (int r2 = 0; r2 < 16; ++r2) {
                float xi[4], xj[4];
                *(float4*)xi = *(const float4*)(smem + r2 * D + ti * 4);
                *(float4*)xj = *(const float4*)(smem + r2 * D + tj * 4);
                #pragma unroll
                for (int a = 0; a < 4; ++a)
                    #pragma unroll
                    for (int b2 = 0; b2 < 4; ++b2)
                        acc[a][b2] += xi[a] * xj[b2];
            }
        }
        #pragma unroll
        for (int a = 0; a < 4; ++a)
            *(float4*)(out + (ti * 4 + a) * D + tj * 4) = *(const float4*)acc[a];
    } else {
        // ---- pos-loss row partial ----
        const int b = bid - (NBI + NBU);
        float* uh  = smem;                       // [64]
        int*   sidx = (int*)(smem + D);          // [200]
        float* red = smem + D + LSEQ;            // [4]

        if (t < LSEQ) sidx[t] = pos_iids[(size_t)b * LSEQ + t];
        if (t >= 192) {
            const int j = t - 192;
            uh[j] = user_W[(size_t)uids[b] * D + j] * h[j];
        }
        __syncthreads();

        const int lane = t & 63;
        const int wave = t >> 6;
        const int p    = lane >> 4;      // 0..3
        const int q    = lane & 15;      // 0..15
        const int base = wave * 4 + p;   // 0..15

        const float4 u4 = *(const float4*)(uh + q * 4);

        int ids[13];
        #pragma unroll
        for (int k = 0; k < 13; ++k) {
            const int l = base + 16 * k;
            ids[k] = (l < LSEQ) ? sidx[l] : ITEM_PAD;
        }
        float4 rows[13];
        #pragma unroll
        for (int k = 0; k < 13; ++k) {
            float4 v = make_float4(0.f, 0.f, 0.f, 0.f);
            if (ids[k] != ITEM_PAD)
                v = *(const float4*)(item_W + (size_t)ids[k] * D + q * 4);
            rows[k] = v;
        }

        float local = 0.f;
        #pragma unroll
        for (int k = 0; k < 13; ++k) {
            float s = u4.x*rows[k].x + u4.y*rows[k].y + u4.z*rows[k].z + u4.w*rows[k].w;
            s += __shfl_xor(s, 1);
            s += __shfl_xor(s, 2);
            s += __shfl_xor(s, 4);
            s += __shfl_xor(s, 8);
            if (q == 0)
                local += (1.0f - NEG_W) * s * s - 2.0f * s;   // s==0 for masked/oob
        }
        local += __shfl_xor(local, 1);
        local += __shfl_xor(local, 2);
        local += __shfl_xor(local, 4);
        local += __shfl_xor(local, 8);
        local += __shfl_xor(local, 16);
        local += __shfl_xor(local, 32);
        if (lane == 0) red[wave] = local;
        __syncthreads();
        if (t == 0)
            ws[POS_OFF + b] = red[0] + red[1] + red[2] + red[3];
    }
}

// ---------------------------------------------------------------------------
// Kernel B: 256 blocks. Block b owns k-slice [b*16, b*16+16) of the 64x64 G.
// Threads: kk = t&15 (k within slice), ps = t>>4 (partial-slice 0..15).
// Reduces Pitem (512) / Puser (64) over partial blocks, applies h x h and
// NEG_W, adds 16 pos partials, stores one float to ws2[b]. No atomics.
// ---------------------------------------------------------------------------
__global__ void reduce_partials(const float* __restrict__ ws,
                                const float* __restrict__ h,
                                float* __restrict__ ws2) {
    __shared__ float rI[4][16];
    __shared__ float rU[4][16];
    const int b  = blockIdx.x;
    const int t  = threadIdx.x;
    const int kk = t & 15;
    const int ps = t >> 4;        // 0..15
    const int lane = t & 63;
    const int wave = t >> 6;
    const int k  = b * 16 + kk;

    float si = 0.f, su = 0.f;
    #pragma unroll 8
    for (int p = ps; p < NBI; p += 16) si += ws[PITEM_OFF + (size_t)p * GSZ + k];
    #pragma unroll
    for (int p = ps; p < NBU; p += 16) su += ws[PUSER_OFF + (size_t)p * GSZ + k];

    // in-wave reduce over the 4 ps values resident in this wave
    si += __shfl_xor(si, 16); si += __shfl_xor(si, 32);
    su += __shfl_xor(su, 16); su += __shfl_xor(su, 32);
    if (lane < 16) { rI[wave][kk] = si; rU[wave][kk] = su; }
    __syncthreads();

    float c = 0.f;
    if (t < 16) {
        const float Gi = rI[0][t] + rI[1][t] + rI[2][t] + rI[3][t];
        const float Gu = rU[0][t] + rU[1][t] + rU[2][t] + rU[3][t];
        const int kg = b * 16 + t;
        const int i = kg >> 6, j = kg & 63;
        c = NEG_W * Gi * Gu * h[i] * h[j] + ws[POS_OFF + b * 16 + t];
    }
    if (wave == 0) {
        c += __shfl_xor(c, 1);
        c += __shfl_xor(c, 2);
        c += __shfl_xor(c, 4);
        c += __shfl_xor(c, 8);
        if (lane == 0) ws2[b] = c;
    }
}

// ---------------------------------------------------------------------------
// Kernel C: final 256-float sum -> out[0].
// ---------------------------------------------------------------------------
__global__ void final_sum(const float* __restrict__ ws2, float* __restrict__ out) {
    __shared__ float red[4];
    const int t = threadIdx.x;
    float s = ws2[t];
    s += __shfl_xor(s, 1);
    s += __shfl_xor(s, 2);
    s += __shfl_xor(s, 4);
    s += __shfl_xor(s, 8);
    s += __shfl_xor(s, 16);
    s += __shfl_xor(s, 32);
    const int lane = t & 63, wave = t >> 6;
    if (lane == 0) red[wave] = s;
    __syncthreads();
    if (t == 0) out[0] = red[0] + red[1] + red[2] + red[3];
}

extern "C" void kernel_launch(void* const* d_in, const int* in_sizes, int n_in,
                              void* d_out, int out_size, void* d_ws, size_t ws_size,
                              hipStream_t stream) {
    const int*   uids     = (const int*)d_in[0];
    const int*   pos_iids = (const int*)d_in[1];
    const float* user_W   = (const float*)d_in[2];
    const float* item_W   = (const float*)d_in[3];
    const float* h        = (const float*)d_in[4];
    float* out = (float*)d_out;
    float* ws  = (float*)d_ws;

    fused_partials<<<NBI + NBU + BATCH, 256, 0, stream>>>(uids, pos_iids, user_W,
                                                          item_W, h, ws);
    reduce_partials<<<256, 256, 0, stream>>>(ws, h, ws + WS2_OFF);
    final_sum<<<1, 256, 0, stream>>>(ws + WS2_OFF, out);
}